// Round 10
// baseline (192.887 us; speedup 1.0000x reference)
//
#include <hip/hip_runtime.h>
#include <hip/hip_bf16.h>
#include <math.h>

// Problem constants
#define BB 8
#define LL 2048
#define CIN 32
#define DD 256
#define UU 40   // sample_k = top-k size
#define NROW (BB*LL)          // 16384
#define NSL  (NROW*DD)        // 4194304 elements per (B,L,D) tensor
#define GB 8                  // GRU cooperative blocks

typedef unsigned short u16;
typedef __attribute__((ext_vector_type(8))) short short8;
typedef __attribute__((ext_vector_type(4))) float f32x4;

__device__ __forceinline__ u16 f2bf(float v) {
    unsigned u = __float_as_uint(v);
    unsigned r = (u + 0x7FFF + ((u >> 16) & 1)) >> 16;   // RNE
    return (u16)r;
}
__device__ __forceinline__ float bf2f(u16 h) {
    return __uint_as_float(((unsigned)h) << 16);
}

// DPP row reduction (VALU pipe). row_shr:N moves data toward HIGHER lanes,
// so the row total accumulates in the HIGHEST lane (15 of 16).
template<int CTRL>
__device__ __forceinline__ float dpp_add(float v) {
    int s = __builtin_amdgcn_update_dpp(0, __float_as_int(v), CTRL, 0xf, 0xf, true);
    return v + __int_as_float(s);
}
__device__ __forceinline__ float row16_sum(float v) {
    v = dpp_add<0x118>(v);  // row_shr:8
    v = dpp_add<0x114>(v);  // row_shr:4
    v = dpp_add<0x112>(v);  // row_shr:2
    v = dpp_add<0x111>(v);  // row_shr:1
    return v;
}
__device__ __forceinline__ float dot4(float4 a, float4 b) {
    return a.x * b.x + a.y * b.y + a.z * b.z + a.w * b.w;
}
// nontemporal float4 load via ext-vector type (builtin rejects HIP_vector_type*)
__device__ __forceinline__ float4 nt_load4(const float* p) {
    f32x4 v = __builtin_nontemporal_load((const f32x4*)p);
    float4 r; r.x = v.x; r.y = v.y; r.z = v.z; r.w = v.w;
    return r;
}

// ---------------------------------------------------------------------------
// Kernel A: src = x @ emb_w + emb_b + pos_encoding -> bf16 hi/lo split
__global__ __launch_bounds__(256) void src_kernel(
    const float* __restrict__ x, const float* __restrict__ emb_w,
    const float* __restrict__ emb_b,
    u16* __restrict__ srch, u16* __restrict__ srcl, float* __restrict__ srcrow)
{
    __shared__ float xs[CIN];
    const int orig = blockIdx.x;
    const int b = orig & 7;
    const int l = orig >> 3;
    const int r = (b << 11) | l;
    const int d = threadIdx.x;
    if (d < CIN) xs[d] = x[(size_t)r * CIN + d];
    __syncthreads();
    float acc = emb_b[d];
#pragma unroll 8
    for (int c = 0; c < CIN; ++c) acc += xs[c] * emb_w[c * DD + d];
    const int i = d >> 1;
    const float ang = (float)l * expf((float)(2 * i) * (-9.210340371976184f / 256.0f));
    const float pe = (d & 1) ? cosf(ang) : sinf(ang);
    const float v = acc + pe;
    const u16 h = f2bf(v);
    srch[(size_t)r * DD + d] = h;
    srcl[(size_t)r * DD + d] = f2bf(v - bf2f(h));
    if (l == LL - 1) srcrow[b * DD + d] = v;
}

// ---------------------------------------------------------------------------
// Kernel A2: split + transpose weights: whT[o][n][k] = bf16(W_o[k][n])
__global__ __launch_bounds__(256) void splitw_kernel(
    const float* __restrict__ wq, const float* __restrict__ wk,
    const float* __restrict__ wv, u16* __restrict__ whT, u16* __restrict__ wlT)
{
    const int o = blockIdx.x, n = blockIdx.y, k = threadIdx.x;
    const float* W = (o == 0) ? wq : (o == 1) ? wk : wv;
    const float v = W[(size_t)k * DD + n];
    const u16 h = f2bf(v);
    whT[((size_t)o << 16) + n * DD + k] = h;
    wlT[((size_t)o << 16) + n * DD + k] = f2bf(v - bf2f(h));
}

// ---------------------------------------------------------------------------
// Kernel B1 v2: Q,K,V via MFMA, bf16x3 split precision, 128x128 tiles.
// grid (128, 2, 3); z: 0->Q 1->K 2->V. 768 blocks = 3/CU, all resident.
// 4 waves per block, each computing a 64x64 quadrant (4x4 fragments).
// NUMERICS BITWISE-IDENTICAL to the 64^2 version (same k-step sequence,
// same 3-term split order per step). Q epilogue writes qrow.
__global__ __launch_bounds__(256) void gemm_qkv_mfma(
    const u16* __restrict__ srch, const u16* __restrict__ srcl,
    const u16* __restrict__ whT, const u16* __restrict__ wlT,
    const float* __restrict__ bq, const float* __restrict__ bk,
    const float* __restrict__ bv,
    float* __restrict__ Qf, float* __restrict__ K, float* __restrict__ V,
    float* __restrict__ qrow)
{
    __shared__ __align__(16) u16 AhS[128][40], AlS[128][40],
                                 BhS[128][40], BlS[128][40];   // 40 KB
    const int t = threadIdx.x;
    const int bx = blockIdx.x;                  // 0..127
    const int mt = (bx & 7) * 16 + (bx >> 3);   // batch (bx&7) -> XCD (bx&7)
    const int bm = mt * 128;
    const int bn = blockIdx.y * 128;            // 0 or 128
    const int o  = blockIdx.z;                  // 0->Q, 1->K, 2->V
    const u16* wh = whT + ((size_t)o << 16);
    const u16* wl = wlT + ((size_t)o << 16);
    const float* bias = (o == 0) ? bq : (o == 1) ? bk : bv;
    float* C = (o == 0) ? Qf : (o == 1) ? K : V;

    const int lane = t & 63, w = t >> 6;
    const int wr = (w >> 1) * 64, wc = (w & 1) * 64;  // wave quadrant origin
    const int frow = lane & 15, kg = (lane >> 4) * 8;

    f32x4 acc[4][4];
#pragma unroll
    for (int mf = 0; mf < 4; ++mf)
#pragma unroll
        for (int nf = 0; nf < 4; ++nf) acc[mf][nf] = (f32x4){0.f, 0.f, 0.f, 0.f};

    for (int ks = 0; ks < 8; ++ks) {
        const int kb = ks * 32;
        // stage 4 buffers of 128 rows x 32 cols; 512 short8 each, 2/thread
#pragma unroll
        for (int e0 = 0; e0 < 512; e0 += 256) {
            const int e = e0 + t;
            const int row = e >> 2, c8 = (e & 3) * 8;
            *(short8*)&AhS[row][c8] = *(const short8*)&srch[(size_t)(bm + row) * DD + kb + c8];
            *(short8*)&AlS[row][c8] = *(const short8*)&srcl[(size_t)(bm + row) * DD + kb + c8];
            *(short8*)&BhS[row][c8] = *(const short8*)&wh[(size_t)(bn + row) * DD + kb + c8];
            *(short8*)&BlS[row][c8] = *(const short8*)&wl[(size_t)(bn + row) * DD + kb + c8];
        }
        __syncthreads();
        // b-fragments once per k-step (reused across all 4 mf rows)
        short8 bhr[4], blr[4];
#pragma unroll
        for (int nf = 0; nf < 4; ++nf) {
            bhr[nf] = *(const short8*)&BhS[wc + nf * 16 + frow][kg];
            blr[nf] = *(const short8*)&BlS[wc + nf * 16 + frow][kg];
        }
#pragma unroll
        for (int mf = 0; mf < 4; ++mf) {
            const short8 ah = *(const short8*)&AhS[wr + mf * 16 + frow][kg];
            const short8 al = *(const short8*)&AlS[wr + mf * 16 + frow][kg];
#pragma unroll
            for (int nf = 0; nf < 4; ++nf) {
                acc[mf][nf] = __builtin_amdgcn_mfma_f32_16x16x32_bf16(al, bhr[nf], acc[mf][nf], 0, 0, 0);
                acc[mf][nf] = __builtin_amdgcn_mfma_f32_16x16x32_bf16(ah, blr[nf], acc[mf][nf], 0, 0, 0);
                acc[mf][nf] = __builtin_amdgcn_mfma_f32_16x16x32_bf16(ah, bhr[nf], acc[mf][nf], 0, 0, 0);
            }
        }
        __syncthreads();
    }
    // C/D layout (HW-verified): col = lane&15, row = (lane>>4)*4 + reg
#pragma unroll
    for (int mf = 0; mf < 4; ++mf) {
#pragma unroll
        for (int nf = 0; nf < 4; ++nf) {
#pragma unroll
            for (int r = 0; r < 4; ++r) {
                const int row = bm + wr + mf * 16 + (lane >> 4) * 4 + r;
                const int col = bn + wc + nf * 16 + (lane & 15);
                const float v = acc[mf][nf][r] + bias[col];
                C[(size_t)row * DD + col] = v;
                if (o == 0 && (row & (LL - 1)) == (LL - 1))
                    qrow[(row >> 11) * DD + col] = v;
            }
        }
    }
}

// ---------------------------------------------------------------------------
// Kernel B2: QK_s probe (R2 structure, best verified 47.4us) + NONTEMPORAL
// hints on the single-use Q and sidx streams. Theory: per-XCD probe working
// set = K(2MB, reused 40x) + Q(2MB, used once) + sidx ~= 4.3MB > 4MB XCD L2;
// the Q stream evicts K, so the gathers fall through to L3 (655MB/47.5us =
// 13.9 TB/s = L3-rate, not L2's 34.5). nt marks Q/sidx evict-first so K
// stays L2-resident. Pure cache hint: loaded bits identical -> output
// bitwise identical. Numerics: same dot4 order, same row16_sum tree,
// same serial max/sum.
__global__ __launch_bounds__(256) void qks_probe(
    const float* __restrict__ Qf, const float* __restrict__ Kf,
    const int* __restrict__ sidx, float* __restrict__ M)
{
    __shared__ float qk[4][UU];
    const int bid = blockIdx.x;
    const int b = bid & 7;              // batch -> XCD b (K L2-resident there)
    const int grp = bid >> 3;           // 0..511 row-group within batch
    const int t = threadIdx.x;
    const int wv = t >> 6;              // wave = row within group
    const int lane = t & 63;
    const int sub = lane >> 4;          // sample slot 0..3
    const int j = lane & 15;
    const int l = grp * 4 + wv;         // row within batch
    const size_t r = ((size_t)b << 11) + l;

    const int* si = sidx + (size_t)l * UU;
    // one coalesced 160B read per row covers all 40 indices (streamed once)
    const int myidx = __builtin_nontemporal_load(si + (lane < UU ? lane : 0));

    const float* q = &Qf[r * DD];
    const float4 q0 = nt_load4(q + j * 16 + 0);
    const float4 q1 = nt_load4(q + j * 16 + 4);
    const float4 q2 = nt_load4(q + j * 16 + 8);
    const float4 q3 = nt_load4(q + j * 16 + 12);
    const float* Kb = Kf + ((size_t)b << 11) * DD;

    // broadcast: idxs[i] = si[i*4 + sub], all available before any K load
    int idxs[UU / 4];
#pragma unroll
    for (int i = 0; i < UU / 4; ++i) idxs[i] = __shfl(myidx, i * 4 + sub);

#pragma unroll
    for (int i = 0; i < UU / 4; ++i) {
        const float4* kr = (const float4*)&Kb[(size_t)idxs[i] * DD];
        float d = dot4(q0, kr[j * 4 + 0]) + dot4(q1, kr[j * 4 + 1])
                + dot4(q2, kr[j * 4 + 2]) + dot4(q3, kr[j * 4 + 3]);
        d = row16_sum(d);
        if (j == 15) qk[wv][i * 4 + sub] = d;
    }
    __syncthreads();
    if (t < 4) {
        float mx = -1e30f, sm = 0.0f;
#pragma unroll
        for (int s = 0; s < UU; ++s) { float v = qk[t][s]; mx = fmaxf(mx, v); sm += v; }
        M[((size_t)b << 11) + grp * 4 + t] = mx - sm * (1.0f / (float)LL);
    }
}

// ---------------------------------------------------------------------------
// Kernel D: flag[b] = (rank of M[b,2047]) < 40
__global__ __launch_bounds__(256) void rank_kernel(
    const float* __restrict__ M, int* __restrict__ flag)
{
    __shared__ int redi[256];
    const int b = blockIdx.x, t = threadIdx.x;
    const float* Mb = M + (size_t)b * LL;
    const float ref = Mb[LL - 1];
    int cnt = 0;
    for (int l = t; l < LL; l += 256)
        if (l != LL - 1 && Mb[l] >= ref) cnt++;
    redi[t] = cnt; __syncthreads();
    for (int s = 128; s; s >>= 1) { if (t < s) redi[t] += redi[t + s]; __syncthreads(); }
    if (t == 0) flag[b] = (redi[0] < UU) ? 1 : 0;
}

// ---------------------------------------------------------------------------
// Kernel E1: raw scores for row l=2047 (DPP), Q row from qrow buffer
__global__ __launch_bounds__(256) void ctx_scores(
    const float* __restrict__ qrow, const float* __restrict__ K,
    const int* __restrict__ flag, float* __restrict__ sc)
{
    const int b = blockIdx.x;
    if (!flag[b]) return;
    const int t = threadIdx.x, grp = t >> 4, j = t & 15;
    const size_t base = (size_t)b * LL * DD;
    const float4* qr = (const float4*)&qrow[b * DD];
    const float4 q0 = qr[j * 4 + 0], q1 = qr[j * 4 + 1],
                 q2 = qr[j * 4 + 2], q3 = qr[j * 4 + 3];
    const int k0 = blockIdx.y * 128 + grp * 8;
#pragma unroll
    for (int i = 0; i < 8; ++i) {
        const int k = k0 + i;
        const float4* kr = (const float4*)&K[base + (size_t)k * DD];
        float d = dot4(q0, kr[j * 4 + 0]) + dot4(q1, kr[j * 4 + 1])
                + dot4(q2, kr[j * 4 + 2]) + dot4(q3, kr[j * 4 + 3]);
        d = row16_sum(d);
        if (j == 15) sc[b * LL + k] = d * (1.0f / 16.0f);
    }
}

// Kernel E2: softmax numerators in place + denominator
__global__ __launch_bounds__(256) void ctx_softmax(
    const int* __restrict__ flag, float* __restrict__ sc, float* __restrict__ ssum)
{
    __shared__ float red[256];
    const int b = blockIdx.x;
    if (!flag[b]) return;
    const int t = threadIdx.x;
    float* s = sc + b * LL;
    float lm = -1e30f;
    for (int k = t; k < LL; k += 256) lm = fmaxf(lm, s[k]);
    red[t] = lm; __syncthreads();
    for (int st = 128; st; st >>= 1) { if (t < st) red[t] = fmaxf(red[t], red[t + st]); __syncthreads(); }
    const float mx = red[0]; __syncthreads();
    float ls = 0.0f;
    for (int k = t; k < LL; k += 256) { float e = expf(s[k] - mx); s[k] = e; ls += e; }
    red[t] = ls; __syncthreads();
    for (int st = 128; st; st >>= 1) { if (t < st) red[t] += red[t + st]; __syncthreads(); }
    if (t == 0) ssum[b] = red[0];
}

// Kernel E3: PV partials
__global__ __launch_bounds__(256) void ctx_pv(
    const float* __restrict__ V, const float* __restrict__ sc,
    const int* __restrict__ flag, float* __restrict__ part)
{
    const int b = blockIdx.x, slice = blockIdx.y;
    const int d = threadIdx.x;
    const size_t base = (size_t)b * LL * DD;
    const int k0 = slice * 256;
    float acc = 0.0f;
    if (flag[b]) {
#pragma unroll 4
        for (int k = k0; k < k0 + 256; ++k)
            acc += sc[b * LL + k] * V[base + (size_t)k * DD + d];
    } else {
#pragma unroll 4
        for (int k = k0; k < k0 + 256; ++k)
            acc += V[base + (size_t)k * DD + d];
    }
    part[(b * 8 + slice) * DD + d] = acc;
}

// ---------------------------------------------------------------------------
__device__ __forceinline__ float block_sum256(float v, float* red) {
    const int t = threadIdx.x;
    __syncthreads();
    red[t] = v; __syncthreads();
    for (int s = 128; s; s >>= 1) { if (t < s) red[t] += red[t + s]; __syncthreads(); }
    return red[0];
}

// Kernel F: per-batch tail at l=2047
__global__ __launch_bounds__(256) void tail_kernel(
    const float* __restrict__ srcrow, const float* __restrict__ part,
    const float* __restrict__ ssum, const int* __restrict__ flag,
    const float* __restrict__ wo, const float* __restrict__ bo,
    const float* __restrict__ c1w, const float* __restrict__ c1b,
    const float* __restrict__ c2w, const float* __restrict__ c2b,
    const float* __restrict__ g1, const float* __restrict__ b1,
    const float* __restrict__ g2, const float* __restrict__ b2,
    const float* __restrict__ gf, const float* __restrict__ bf,
    float* __restrict__ enc)
{
    __shared__ float xs[DD];
    __shared__ float red[DD];
    const int b = blockIdx.x, d = threadIdx.x;

    float cv = 0.0f;
#pragma unroll
    for (int i = 0; i < 8; ++i) cv += part[(b * 8 + i) * DD + d];
    cv = flag[b] ? cv / ssum[b] : cv * (1.0f / (float)LL);

    xs[d] = cv; __syncthreads();
    float o = bo[d];
    for (int j = 0; j < DD; ++j) o += xs[j] * wo[j * DD + d];
    const float v = srcrow[b * DD + d] + o;

    float mu = block_sum256(v, red) * (1.0f / DD);
    float dv = v - mu;
    float var = block_sum256(dv * dv, red) * (1.0f / DD);
    const float x1 = dv * rsqrtf(var + 1e-5f) * g1[d] + b1[d];

    __syncthreads(); xs[d] = x1; __syncthreads();
    float a = c1b[d];
    for (int j = 0; j < DD; ++j) a += xs[j] * c1w[j * DD + d];
    a = 0.5f * a * (1.0f + erff(a * 0.70710678118654752f));

    __syncthreads(); xs[d] = a; __syncthreads();
    float y = c2b[d];
    for (int j = 0; j < DD; ++j) y += xs[j] * c2w[j * DD + d];

    float t2 = x1 + y;
    mu = block_sum256(t2, red) * (1.0f / DD);
    dv = t2 - mu;
    var = block_sum256(dv * dv, red) * (1.0f / DD);
    float t3 = dv * rsqrtf(var + 1e-5f) * g2[d] + b2[d];

    mu = block_sum256(t3, red) * (1.0f / DD);
    dv = t3 - mu;
    var = block_sum256(dv * dv, red) * (1.0f / DD);
    enc[b * DD + d] = dv * rsqrtf(var + 1e-5f) * gf[d] + bf[d];
}

// ---------------------------------------------------------------------------
// GRU v3: output-partitioned across GB=8 blocks, fence-free tagged exchange.
__global__ __launch_bounds__(768) void gru_coop_kernel(
    const float* __restrict__ enc, const float* __restrict__ wih,
    const float* __restrict__ whh, const float* __restrict__ bih,
    const float* __restrict__ bhh, const float* __restrict__ fcw,
    const float* __restrict__ fcb,
    unsigned long long* __restrict__ hpub,   // [256], zeroed per launch
    float* __restrict__ out)
{
    __shared__ float whhS[96][257];   // 98.7 KB
    __shared__ float encS[BB][260];
    __shared__ float giS[96][8];
    __shared__ float hS[DD];
    __shared__ float ghS[96];
    __shared__ float red[256];
    const int g = blockIdx.x, t = threadIdx.x;

#pragma unroll
    for (int i = 0; i < 8; ++i) {
        const int f4 = t + 768 * i;          // 96 rows x 64 float4
        const int lr = f4 >> 6, c4 = f4 & 63;
        const int R = (lr >> 5) * 256 + g * 32 + (lr & 31);
        const float4 w = *(const float4*)&whh[(size_t)R * DD + c4 * 4];
        whhS[lr][c4 * 4 + 0] = w.x; whhS[lr][c4 * 4 + 1] = w.y;
        whhS[lr][c4 * 4 + 2] = w.z; whhS[lr][c4 * 4 + 3] = w.w;
    }
    for (int e = t; e < BB * DD; e += 768) encS[e >> 8][e & 255] = enc[e];
    if (t < DD) hS[t] = 0.0f;
    __syncthreads();

    {
        const int lr = t >> 3, b = t & 7;
        const int R = (lr >> 5) * 256 + g * 32 + (lr & 31);
        float acc = bih[R];
        const float4* w4 = (const float4*)&wih[(size_t)R * DD];
#pragma unroll 8
        for (int jc = 0; jc < 64; ++jc) {
            const float4 w = w4[jc];
            acc += encS[b][jc * 4 + 0] * w.x + encS[b][jc * 4 + 1] * w.y
                 + encS[b][jc * 4 + 2] * w.z + encS[b][jc * 4 + 3] * w.w;
        }
        giS[lr][b] = acc;
    }
    __syncthreads();

    for (int step = 1; step <= BB; ++step) {
        const int b = step - 1;
        const int lr = t >> 3, s = t & 7;
        float p = 0.0f;
#pragma unroll
        for (int k = 0; k < 32; ++k) {
            const int c = s * 32 + ((k + s * 4) & 31);
            p += whhS[lr][c] * hS[c];
        }
        p = dpp_add<0x114>(p); p = dpp_add<0x112>(p); p = dpp_add<0x111>(p);
        if (s == 7) ghS[lr] = p + bhh[(lr >> 5) * 256 + g * 32 + (lr & 31)];
        __syncthreads();

        if (t < 32) {
            const float r  = 1.0f / (1.0f + expf(-(giS[t][b]      + ghS[t])));
            const float z  = 1.0f / (1.0f + expf(-(giS[32 + t][b] + ghS[32 + t])));
            const float n  = tanhf(giS[64 + t][b] + r * ghS[64 + t]);
            const float hnew = (1.0f - z) * n + z * hS[g * 32 + t];
            const unsigned long long w =
                ((unsigned long long)(unsigned)step << 32) | (unsigned long long)__float_as_uint(hnew);
            __hip_atomic_store(&hpub[g * 32 + t], w, __ATOMIC_RELAXED, __HIP_MEMORY_SCOPE_AGENT);
        }
        __syncthreads();
        if (t < DD) {
            unsigned long long w;
            do {
                w = __hip_atomic_load(&hpub[t], __ATOMIC_RELAXED, __HIP_MEMORY_SCOPE_AGENT);
            } while ((int)(w >> 32) != step);
            hS[t] = __uint_as_float((unsigned)w);
        }
        __syncthreads();

        if (g == 0) {
            if (t < DD) red[t] = hS[t] * fcw[t];
            __syncthreads();
            for (int st2 = 128; st2; st2 >>= 1) { if (t < st2) red[t] += red[t + st2]; __syncthreads(); }
            if (t == 0) out[b] = red[0] + fcb[0];
            __syncthreads();
        }
    }
}

// ---------------------------------------------------------------------------
extern "C" void kernel_launch(void* const* d_in, const int* in_sizes, int n_in,
                              void* d_out, int out_size, void* d_ws, size_t ws_size,
                              hipStream_t stream)
{
    const float* x      = (const float*)d_in[0];
    const int*   sidx   = (const int*)  d_in[1];
    const float* emb_w  = (const float*)d_in[2];
    const float* emb_b  = (const float*)d_in[3];
    const float* wq     = (const float*)d_in[4];
    const float* bq     = (const float*)d_in[5];
    const float* wk     = (const float*)d_in[6];
    const float* bk     = (const float*)d_in[7];
    const float* wv     = (const float*)d_in[8];
    const float* bv     = (const float*)d_in[9];
    const float* wo     = (const float*)d_in[10];
    const float* bo     = (const float*)d_in[11];
    const float* c1w    = (const float*)d_in[12];
    const float* c1b    = (const float*)d_in[13];
    const float* c2w    = (const float*)d_in[14];
    const float* c2b    = (const float*)d_in[15];
    const float* ln1g   = (const float*)d_in[16];
    const float* ln1b   = (const float*)d_in[17];
    const float* ln2g   = (const float*)d_in[18];
    const float* ln2b   = (const float*)d_in[19];
    const float* lnfg   = (const float*)d_in[20];
    const float* lnfb   = (const float*)d_in[21];
    const float* wih    = (const float*)d_in[22];
    const float* whh    = (const float*)d_in[23];
    const float* bih    = (const float*)d_in[24];
    const float* bhh    = (const float*)d_in[25];
    const float* fcw    = (const float*)d_in[26];
    const float* fcb    = (const float*)d_in[27];

    float* ws  = (float*)d_ws;
    float* K    = ws;                    // NSL
    float* V    = K + NSL;               // NSL
    float* Mv   = V + NSL;               // 16384
    int*   flag = (int*)(Mv + NROW);     // 16
    float* sc   = (float*)(flag + 16);   // 8*2048
    float* ssum = sc + BB * LL;          // 16
    float* part = ssum + 16;             // 8*8*256
    float* srcrow = part + BB * 8 * DD;  // 2048
    float* qrow = srcrow + BB * DD;      // 2048
    float* enc  = qrow + BB * DD;        // 2048
    unsigned long long* hpub = (unsigned long long*)(enc + BB * DD); // 256
    u16* srch = (u16*)(hpub + 256);      // NSL bf16
    u16* srcl = srch + NSL;              // NSL bf16
    u16* whT  = srcl + NSL;              // 3*65536
    u16* wlT  = whT + 3 * 65536;         // 3*65536
    float* Qf = (float*)(wlT + 3 * 65536); // NSL fp32 (full Q, probe input)

    hipMemsetAsync(hpub, 0, 256 * sizeof(unsigned long long), stream);

    splitw_kernel<<<dim3(3, 256), 256, 0, stream>>>(wq, wk, wv, whT, wlT);
    src_kernel<<<NROW, 256, 0, stream>>>(x, emb_w, emb_b, srch, srcl, srcrow);
    gemm_qkv_mfma<<<dim3(128, 2, 3), 256, 0, stream>>>(srch, srcl, whT, wlT,
                                                       bq, bk, bv, Qf, K, V, qrow);
    qks_probe<<<NROW / 4, 256, 0, stream>>>(Qf, K, sidx, Mv);
    rank_kernel<<<BB, 256, 0, stream>>>(Mv, flag);
    ctx_scores<<<dim3(BB, 16), 256, 0, stream>>>(qrow, K, flag, sc);
    ctx_softmax<<<BB, 256, 0, stream>>>(flag, sc, ssum);
    ctx_pv<<<dim3(BB, 8), 256, 0, stream>>>(V, sc, flag, part);
    tail_kernel<<<BB, 256, 0, stream>>>(srcrow, part, ssum, flag, wo, bo,
                                        c1w, c1b, c2w, c2b,
                                        ln1g, ln1b, ln2g, ln2b, lnfg, lnfb, enc);
    gru_coop_kernel<<<GB, 768, 0, stream>>>(enc, wih, whh, bih, bhh, fcw, fcb,
                                            hpub, (float*)d_out);
}

// Round 11
// 172.658 us; speedup vs baseline: 1.1172x; 1.1172x over previous
//
#include <hip/hip_runtime.h>
#include <hip/hip_bf16.h>
#include <math.h>

// Problem constants
#define BB 8
#define LL 2048
#define CIN 32
#define DD 256
#define UU 40   // sample_k = top-k size
#define NROW (BB*LL)          // 16384
#define NSL  (NROW*DD)        // 4194304 elements per (B,L,D) tensor
#define GB 8                  // GRU cooperative blocks

typedef unsigned short u16;
typedef __attribute__((ext_vector_type(8))) short short8;
typedef __attribute__((ext_vector_type(4))) float f32x4;

__device__ __forceinline__ u16 f2bf(float v) {
    unsigned u = __float_as_uint(v);
    unsigned r = (u + 0x7FFF + ((u >> 16) & 1)) >> 16;   // RNE
    return (u16)r;
}
__device__ __forceinline__ float bf2f(u16 h) {
    return __uint_as_float(((unsigned)h) << 16);
}

// DPP row reduction (VALU pipe). row_shr:N moves data toward HIGHER lanes,
// so the row total accumulates in the HIGHEST lane (15 of 16).
template<int CTRL>
__device__ __forceinline__ float dpp_add(float v) {
    int s = __builtin_amdgcn_update_dpp(0, __float_as_int(v), CTRL, 0xf, 0xf, true);
    return v + __int_as_float(s);
}
__device__ __forceinline__ float row16_sum(float v) {
    v = dpp_add<0x118>(v);  // row_shr:8
    v = dpp_add<0x114>(v);  // row_shr:4
    v = dpp_add<0x112>(v);  // row_shr:2
    v = dpp_add<0x111>(v);  // row_shr:1
    return v;
}
__device__ __forceinline__ float dot4(float4 a, float4 b) {
    return a.x * b.x + a.y * b.y + a.z * b.z + a.w * b.w;
}

// ---------------------------------------------------------------------------
// Kernel A: src = x @ emb_w + emb_b + pos_encoding -> bf16 hi/lo split
__global__ __launch_bounds__(256) void src_kernel(
    const float* __restrict__ x, const float* __restrict__ emb_w,
    const float* __restrict__ emb_b,
    u16* __restrict__ srch, u16* __restrict__ srcl, float* __restrict__ srcrow)
{
    __shared__ float xs[CIN];
    const int orig = blockIdx.x;
    const int b = orig & 7;
    const int l = orig >> 3;
    const int r = (b << 11) | l;
    const int d = threadIdx.x;
    if (d < CIN) xs[d] = x[(size_t)r * CIN + d];
    __syncthreads();
    float acc = emb_b[d];
#pragma unroll 8
    for (int c = 0; c < CIN; ++c) acc += xs[c] * emb_w[c * DD + d];
    const int i = d >> 1;
    const float ang = (float)l * expf((float)(2 * i) * (-9.210340371976184f / 256.0f));
    const float pe = (d & 1) ? cosf(ang) : sinf(ang);
    const float v = acc + pe;
    const u16 h = f2bf(v);
    srch[(size_t)r * DD + d] = h;
    srcl[(size_t)r * DD + d] = f2bf(v - bf2f(h));
    if (l == LL - 1) srcrow[b * DD + d] = v;
}

// ---------------------------------------------------------------------------
// Kernel A2: split + transpose weights: whT[o][n][k] = bf16(W_o[k][n])
__global__ __launch_bounds__(256) void splitw_kernel(
    const float* __restrict__ wq, const float* __restrict__ wk,
    const float* __restrict__ wv, u16* __restrict__ whT, u16* __restrict__ wlT)
{
    const int o = blockIdx.x, n = blockIdx.y, k = threadIdx.x;
    const float* W = (o == 0) ? wq : (o == 1) ? wk : wv;
    const float v = W[(size_t)k * DD + n];
    const u16 h = f2bf(v);
    whT[((size_t)o << 16) + n * DD + k] = h;
    wlT[((size_t)o << 16) + n * DD + k] = f2bf(v - bf2f(h));
}

// ---------------------------------------------------------------------------
// Kernel B1 v2: Q,K,V via MFMA, bf16x3 split precision, 128x128 tiles.
// grid (128, 2, 3); z: 0->Q 1->K 2->V. 768 blocks = 3/CU, all resident.
// 4 waves per block, each computing a 64x64 quadrant (4x4 fragments).
// NUMERICS BITWISE-IDENTICAL to the 64^2 version (same k-step sequence,
// same 3-term split order per step). Q epilogue writes qrow.
__global__ __launch_bounds__(256) void gemm_qkv_mfma(
    const u16* __restrict__ srch, const u16* __restrict__ srcl,
    const u16* __restrict__ whT, const u16* __restrict__ wlT,
    const float* __restrict__ bq, const float* __restrict__ bk,
    const float* __restrict__ bv,
    float* __restrict__ Qf, float* __restrict__ K, float* __restrict__ V,
    float* __restrict__ qrow)
{
    __shared__ __align__(16) u16 AhS[128][40], AlS[128][40],
                                 BhS[128][40], BlS[128][40];   // 40 KB
    const int t = threadIdx.x;
    const int bx = blockIdx.x;                  // 0..127
    const int mt = (bx & 7) * 16 + (bx >> 3);   // batch (bx&7) -> XCD (bx&7)
    const int bm = mt * 128;
    const int bn = blockIdx.y * 128;            // 0 or 128
    const int o  = blockIdx.z;                  // 0->Q, 1->K, 2->V
    const u16* wh = whT + ((size_t)o << 16);
    const u16* wl = wlT + ((size_t)o << 16);
    const float* bias = (o == 0) ? bq : (o == 1) ? bk : bv;
    float* C = (o == 0) ? Qf : (o == 1) ? K : V;

    const int lane = t & 63, w = t >> 6;
    const int wr = (w >> 1) * 64, wc = (w & 1) * 64;  // wave quadrant origin
    const int frow = lane & 15, kg = (lane >> 4) * 8;

    f32x4 acc[4][4];
#pragma unroll
    for (int mf = 0; mf < 4; ++mf)
#pragma unroll
        for (int nf = 0; nf < 4; ++nf) acc[mf][nf] = (f32x4){0.f, 0.f, 0.f, 0.f};

    for (int ks = 0; ks < 8; ++ks) {
        const int kb = ks * 32;
        // stage 4 buffers of 128 rows x 32 cols; 512 short8 each, 2/thread
#pragma unroll
        for (int e0 = 0; e0 < 512; e0 += 256) {
            const int e = e0 + t;
            const int row = e >> 2, c8 = (e & 3) * 8;
            *(short8*)&AhS[row][c8] = *(const short8*)&srch[(size_t)(bm + row) * DD + kb + c8];
            *(short8*)&AlS[row][c8] = *(const short8*)&srcl[(size_t)(bm + row) * DD + kb + c8];
            *(short8*)&BhS[row][c8] = *(const short8*)&wh[(size_t)(bn + row) * DD + kb + c8];
            *(short8*)&BlS[row][c8] = *(const short8*)&wl[(size_t)(bn + row) * DD + kb + c8];
        }
        __syncthreads();
        // b-fragments once per k-step (reused across all 4 mf rows)
        short8 bhr[4], blr[4];
#pragma unroll
        for (int nf = 0; nf < 4; ++nf) {
            bhr[nf] = *(const short8*)&BhS[wc + nf * 16 + frow][kg];
            blr[nf] = *(const short8*)&BlS[wc + nf * 16 + frow][kg];
        }
#pragma unroll
        for (int mf = 0; mf < 4; ++mf) {
            const short8 ah = *(const short8*)&AhS[wr + mf * 16 + frow][kg];
            const short8 al = *(const short8*)&AlS[wr + mf * 16 + frow][kg];
#pragma unroll
            for (int nf = 0; nf < 4; ++nf) {
                acc[mf][nf] = __builtin_amdgcn_mfma_f32_16x16x32_bf16(al, bhr[nf], acc[mf][nf], 0, 0, 0);
                acc[mf][nf] = __builtin_amdgcn_mfma_f32_16x16x32_bf16(ah, blr[nf], acc[mf][nf], 0, 0, 0);
                acc[mf][nf] = __builtin_amdgcn_mfma_f32_16x16x32_bf16(ah, bhr[nf], acc[mf][nf], 0, 0, 0);
            }
        }
        __syncthreads();
    }
    // C/D layout (HW-verified): col = lane&15, row = (lane>>4)*4 + reg
#pragma unroll
    for (int mf = 0; mf < 4; ++mf) {
#pragma unroll
        for (int nf = 0; nf < 4; ++nf) {
#pragma unroll
            for (int r = 0; r < 4; ++r) {
                const int row = bm + wr + mf * 16 + (lane >> 4) * 4 + r;
                const int col = bn + wc + nf * 16 + (lane & 15);
                const float v = acc[mf][nf][r] + bias[col];
                C[(size_t)row * DD + col] = v;
                if (o == 0 && (row & (LL - 1)) == (LL - 1))
                    qrow[(row >> 11) * DD + col] = v;
            }
        }
    }
}

// ---------------------------------------------------------------------------
// Kernel B2 v6: FULLY-COALESCED gather. One wave per row; for each of the
// 40 samples, ALL 64 lanes read the K row contiguously (lane l takes
// k[4l..4l+4), 64x16B = one clean 1KB run per instruction).
// Why: the old 16-lane-sub-group layout made each load instruction touch
// 64 discontiguous 16B chunks at 64B stride across 4 different K rows —
// maximal TA fragmentation, which is the transaction-issue wall that kept
// the probe pinned at 47us regardless of ILP/DMA/cache hints (R2-R10).
// Reduction: per-sample dot4 -> row16_sum within each 16-lane row -> 4
// partials to LDS -> one thread per row combines ((p0+p1)+p2)+p3 serially
// and takes max/mean. M's reduction tree changes (allowed: M feeds only
// the discrete rank/flag; our M already differs from JAX's einsum order
// and passes with absmax 0.0; flag flips need exact fp32 ties).
// nt hints removed (R10: regression).
__global__ __launch_bounds__(256) void qks_probe(
    const float* __restrict__ Qf, const float* __restrict__ Kf,
    const int* __restrict__ sidx, float* __restrict__ M)
{
    __shared__ float qkp[4][4][UU];   // [wave][sub16][sample] partials
    const int bid = blockIdx.x;
    const int b = bid & 7;              // batch -> XCD b (K L2-resident there)
    const int grp = bid >> 3;           // 0..511 row-group within batch
    const int t = threadIdx.x;
    const int wv = t >> 6;              // wave = row within group
    const int lane = t & 63;
    const int sub = lane >> 4;          // 16-lane row within the wave
    const int j = lane & 15;
    const int l = grp * 4 + wv;         // row within batch
    const size_t r = ((size_t)b << 11) + l;

    const int* si = sidx + (size_t)l * UU;
    // one coalesced 160B read per row covers all 40 indices
    const int myidx = si[lane < UU ? lane : 0];

    // per-lane q chunk: 4 consecutive floats (coalesced wave read of 1KB)
    const float4 q = *(const float4*)&Qf[r * DD + lane * 4];
    const float* Kb = Kf + ((size_t)b << 11) * DD;

#pragma unroll
    for (int s = 0; s < UU; ++s) {
        // wave-uniform row index (SGPR) -> saddr+lane*16B coalesced load
        const int idx = __builtin_amdgcn_readlane(myidx, s);
        const float4 kv = *(const float4*)&Kb[(size_t)idx * DD + lane * 4];
        float d = dot4(q, kv);
        d = row16_sum(d);               // lane j==15 of each 16-row holds partial
        if (j == 15) qkp[wv][sub][s] = d;
    }
    __syncthreads();
    if (t < 4) {
        float mx = -1e30f, sm = 0.0f;
#pragma unroll
        for (int s = 0; s < UU; ++s) {
            const float v = ((qkp[t][0][s] + qkp[t][1][s])
                           + qkp[t][2][s]) + qkp[t][3][s];
            mx = fmaxf(mx, v); sm += v;
        }
        M[((size_t)b << 11) + grp * 4 + t] = mx - sm * (1.0f / (float)LL);
    }
}

// ---------------------------------------------------------------------------
// Kernel D: flag[b] = (rank of M[b,2047]) < 40
__global__ __launch_bounds__(256) void rank_kernel(
    const float* __restrict__ M, int* __restrict__ flag)
{
    __shared__ int redi[256];
    const int b = blockIdx.x, t = threadIdx.x;
    const float* Mb = M + (size_t)b * LL;
    const float ref = Mb[LL - 1];
    int cnt = 0;
    for (int l = t; l < LL; l += 256)
        if (l != LL - 1 && Mb[l] >= ref) cnt++;
    redi[t] = cnt; __syncthreads();
    for (int s = 128; s; s >>= 1) { if (t < s) redi[t] += redi[t + s]; __syncthreads(); }
    if (t == 0) flag[b] = (redi[0] < UU) ? 1 : 0;
}

// ---------------------------------------------------------------------------
// Kernel E1: raw scores for row l=2047 (DPP), Q row from qrow buffer
__global__ __launch_bounds__(256) void ctx_scores(
    const float* __restrict__ qrow, const float* __restrict__ K,
    const int* __restrict__ flag, float* __restrict__ sc)
{
    const int b = blockIdx.x;
    if (!flag[b]) return;
    const int t = threadIdx.x, grp = t >> 4, j = t & 15;
    const size_t base = (size_t)b * LL * DD;
    const float4* qr = (const float4*)&qrow[b * DD];
    const float4 q0 = qr[j * 4 + 0], q1 = qr[j * 4 + 1],
                 q2 = qr[j * 4 + 2], q3 = qr[j * 4 + 3];
    const int k0 = blockIdx.y * 128 + grp * 8;
#pragma unroll
    for (int i = 0; i < 8; ++i) {
        const int k = k0 + i;
        const float4* kr = (const float4*)&K[base + (size_t)k * DD];
        float d = dot4(q0, kr[j * 4 + 0]) + dot4(q1, kr[j * 4 + 1])
                + dot4(q2, kr[j * 4 + 2]) + dot4(q3, kr[j * 4 + 3]);
        d = row16_sum(d);
        if (j == 15) sc[b * LL + k] = d * (1.0f / 16.0f);
    }
}

// Kernel E2: softmax numerators in place + denominator
__global__ __launch_bounds__(256) void ctx_softmax(
    const int* __restrict__ flag, float* __restrict__ sc, float* __restrict__ ssum)
{
    __shared__ float red[256];
    const int b = blockIdx.x;
    if (!flag[b]) return;
    const int t = threadIdx.x;
    float* s = sc + b * LL;
    float lm = -1e30f;
    for (int k = t; k < LL; k += 256) lm = fmaxf(lm, s[k]);
    red[t] = lm; __syncthreads();
    for (int st = 128; st; st >>= 1) { if (t < st) red[t] = fmaxf(red[t], red[t + st]); __syncthreads(); }
    const float mx = red[0]; __syncthreads();
    float ls = 0.0f;
    for (int k = t; k < LL; k += 256) { float e = expf(s[k] - mx); s[k] = e; ls += e; }
    red[t] = ls; __syncthreads();
    for (int st = 128; st; st >>= 1) { if (t < st) red[t] += red[t + st]; __syncthreads(); }
    if (t == 0) ssum[b] = red[0];
}

// Kernel E3: PV partials
__global__ __launch_bounds__(256) void ctx_pv(
    const float* __restrict__ V, const float* __restrict__ sc,
    const int* __restrict__ flag, float* __restrict__ part)
{
    const int b = blockIdx.x, slice = blockIdx.y;
    const int d = threadIdx.x;
    const size_t base = (size_t)b * LL * DD;
    const int k0 = slice * 256;
    float acc = 0.0f;
    if (flag[b]) {
#pragma unroll 4
        for (int k = k0; k < k0 + 256; ++k)
            acc += sc[b * LL + k] * V[base + (size_t)k * DD + d];
    } else {
#pragma unroll 4
        for (int k = k0; k < k0 + 256; ++k)
            acc += V[base + (size_t)k * DD + d];
    }
    part[(b * 8 + slice) * DD + d] = acc;
}

// ---------------------------------------------------------------------------
__device__ __forceinline__ float block_sum256(float v, float* red) {
    const int t = threadIdx.x;
    __syncthreads();
    red[t] = v; __syncthreads();
    for (int s = 128; s; s >>= 1) { if (t < s) red[t] += red[t + s]; __syncthreads(); }
    return red[0];
}

// Kernel F: per-batch tail at l=2047
__global__ __launch_bounds__(256) void tail_kernel(
    const float* __restrict__ srcrow, const float* __restrict__ part,
    const float* __restrict__ ssum, const int* __restrict__ flag,
    const float* __restrict__ wo, const float* __restrict__ bo,
    const float* __restrict__ c1w, const float* __restrict__ c1b,
    const float* __restrict__ c2w, const float* __restrict__ c2b,
    const float* __restrict__ g1, const float* __restrict__ b1,
    const float* __restrict__ g2, const float* __restrict__ b2,
    const float* __restrict__ gf, const float* __restrict__ bf,
    float* __restrict__ enc)
{
    __shared__ float xs[DD];
    __shared__ float red[DD];
    const int b = blockIdx.x, d = threadIdx.x;

    float cv = 0.0f;
#pragma unroll
    for (int i = 0; i < 8; ++i) cv += part[(b * 8 + i) * DD + d];
    cv = flag[b] ? cv / ssum[b] : cv * (1.0f / (float)LL);

    xs[d] = cv; __syncthreads();
    float o = bo[d];
    for (int j = 0; j < DD; ++j) o += xs[j] * wo[j * DD + d];
    const float v = srcrow[b * DD + d] + o;

    float mu = block_sum256(v, red) * (1.0f / DD);
    float dv = v - mu;
    float var = block_sum256(dv * dv, red) * (1.0f / DD);
    const float x1 = dv * rsqrtf(var + 1e-5f) * g1[d] + b1[d];

    __syncthreads(); xs[d] = x1; __syncthreads();
    float a = c1b[d];
    for (int j = 0; j < DD; ++j) a += xs[j] * c1w[j * DD + d];
    a = 0.5f * a * (1.0f + erff(a * 0.70710678118654752f));

    __syncthreads(); xs[d] = a; __syncthreads();
    float y = c2b[d];
    for (int j = 0; j < DD; ++j) y += xs[j] * c2w[j * DD + d];

    float t2 = x1 + y;
    mu = block_sum256(t2, red) * (1.0f / DD);
    dv = t2 - mu;
    var = block_sum256(dv * dv, red) * (1.0f / DD);
    float t3 = dv * rsqrtf(var + 1e-5f) * g2[d] + b2[d];

    mu = block_sum256(t3, red) * (1.0f / DD);
    dv = t3 - mu;
    var = block_sum256(dv * dv, red) * (1.0f / DD);
    enc[b * DD + d] = dv * rsqrtf(var + 1e-5f) * gf[d] + bf[d];
}

// ---------------------------------------------------------------------------
// GRU v3: output-partitioned across GB=8 blocks, fence-free tagged exchange.
__global__ __launch_bounds__(768) void gru_coop_kernel(
    const float* __restrict__ enc, const float* __restrict__ wih,
    const float* __restrict__ whh, const float* __restrict__ bih,
    const float* __restrict__ bhh, const float* __restrict__ fcw,
    const float* __restrict__ fcb,
    unsigned long long* __restrict__ hpub,   // [256], zeroed per launch
    float* __restrict__ out)
{
    __shared__ float whhS[96][257];   // 98.7 KB
    __shared__ float encS[BB][260];
    __shared__ float giS[96][8];
    __shared__ float hS[DD];
    __shared__ float ghS[96];
    __shared__ float red[256];
    const int g = blockIdx.x, t = threadIdx.x;

#pragma unroll
    for (int i = 0; i < 8; ++i) {
        const int f4 = t + 768 * i;          // 96 rows x 64 float4
        const int lr = f4 >> 6, c4 = f4 & 63;
        const int R = (lr >> 5) * 256 + g * 32 + (lr & 31);
        const float4 w = *(const float4*)&whh[(size_t)R * DD + c4 * 4];
        whhS[lr][c4 * 4 + 0] = w.x; whhS[lr][c4 * 4 + 1] = w.y;
        whhS[lr][c4 * 4 + 2] = w.z; whhS[lr][c4 * 4 + 3] = w.w;
    }
    for (int e = t; e < BB * DD; e += 768) encS[e >> 8][e & 255] = enc[e];
    if (t < DD) hS[t] = 0.0f;
    __syncthreads();

    {
        const int lr = t >> 3, b = t & 7;
        const int R = (lr >> 5) * 256 + g * 32 + (lr & 31);
        float acc = bih[R];
        const float4* w4 = (const float4*)&wih[(size_t)R * DD];
#pragma unroll 8
        for (int jc = 0; jc < 64; ++jc) {
            const float4 w = w4[jc];
            acc += encS[b][jc * 4 + 0] * w.x + encS[b][jc * 4 + 1] * w.y
                 + encS[b][jc * 4 + 2] * w.z + encS[b][jc * 4 + 3] * w.w;
        }
        giS[lr][b] = acc;
    }
    __syncthreads();

    for (int step = 1; step <= BB; ++step) {
        const int b = step - 1;
        const int lr = t >> 3, s = t & 7;
        float p = 0.0f;
#pragma unroll
        for (int k = 0; k < 32; ++k) {
            const int c = s * 32 + ((k + s * 4) & 31);
            p += whhS[lr][c] * hS[c];
        }
        p = dpp_add<0x114>(p); p = dpp_add<0x112>(p); p = dpp_add<0x111>(p);
        if (s == 7) ghS[lr] = p + bhh[(lr >> 5) * 256 + g * 32 + (lr & 31)];
        __syncthreads();

        if (t < 32) {
            const float r  = 1.0f / (1.0f + expf(-(giS[t][b]      + ghS[t])));
            const float z  = 1.0f / (1.0f + expf(-(giS[32 + t][b] + ghS[32 + t])));
            const float n  = tanhf(giS[64 + t][b] + r * ghS[64 + t]);
            const float hnew = (1.0f - z) * n + z * hS[g * 32 + t];
            const unsigned long long w =
                ((unsigned long long)(unsigned)step << 32) | (unsigned long long)__float_as_uint(hnew);
            __hip_atomic_store(&hpub[g * 32 + t], w, __ATOMIC_RELAXED, __HIP_MEMORY_SCOPE_AGENT);
        }
        __syncthreads();
        if (t < DD) {
            unsigned long long w;
            do {
                w = __hip_atomic_load(&hpub[t], __ATOMIC_RELAXED, __HIP_MEMORY_SCOPE_AGENT);
            } while ((int)(w >> 32) != step);
            hS[t] = __uint_as_float((unsigned)w);
        }
        __syncthreads();

        if (g == 0) {
            if (t < DD) red[t] = hS[t] * fcw[t];
            __syncthreads();
            for (int st2 = 128; st2; st2 >>= 1) { if (t < st2) red[t] += red[t + st2]; __syncthreads(); }
            if (t == 0) out[b] = red[0] + fcb[0];
            __syncthreads();
        }
    }
}

// ---------------------------------------------------------------------------
extern "C" void kernel_launch(void* const* d_in, const int* in_sizes, int n_in,
                              void* d_out, int out_size, void* d_ws, size_t ws_size,
                              hipStream_t stream)
{
    const float* x      = (const float*)d_in[0];
    const int*   sidx   = (const int*)  d_in[1];
    const float* emb_w  = (const float*)d_in[2];
    const float* emb_b  = (const float*)d_in[3];
    const float* wq     = (const float*)d_in[4];
    const float* bq     = (const float*)d_in[5];
    const float* wk     = (const float*)d_in[6];
    const float* bk     = (const float*)d_in[7];
    const float* wv     = (const float*)d_in[8];
    const float* bv     = (const float*)d_in[9];
    const float* wo     = (const float*)d_in[10];
    const float* bo     = (const float*)d_in[11];
    const float* c1w    = (const float*)d_in[12];
    const float* c1b    = (const float*)d_in[13];
    const float* c2w    = (const float*)d_in[14];
    const float* c2b    = (const float*)d_in[15];
    const float* ln1g   = (const float*)d_in[16];
    const float* ln1b   = (const float*)d_in[17];
    const float* ln2g   = (const float*)d_in[18];
    const float* ln2b   = (const float*)d_in[19];
    const float* lnfg   = (const float*)d_in[20];
    const float* lnfb   = (const float*)d_in[21];
    const float* wih    = (const float*)d_in[22];
    const float* whh    = (const float*)d_in[23];
    const float* bih    = (const float*)d_in[24];
    const float* bhh    = (const float*)d_in[25];
    const float* fcw    = (const float*)d_in[26];
    const float* fcb    = (const float*)d_in[27];

    float* ws  = (float*)d_ws;
    float* K    = ws;                    // NSL
    float* V    = K + NSL;               // NSL
    float* Mv   = V + NSL;               // 16384
    int*   flag = (int*)(Mv + NROW);     // 16
    float* sc   = (float*)(flag + 16);   // 8*2048
    float* ssum = sc + BB * LL;          // 16
    float* part = ssum + 16;             // 8*8*256
    float* srcrow = part + BB * 8 * DD;  // 2048
    float* qrow = srcrow + BB * DD;      // 2048
    float* enc  = qrow + BB * DD;        // 2048
    unsigned long long* hpub = (unsigned long long*)(enc + BB * DD); // 256
    u16* srch = (u16*)(hpub + 256);      // NSL bf16
    u16* srcl = srch + NSL;              // NSL bf16
    u16* whT  = srcl + NSL;              // 3*65536
    u16* wlT  = whT + 3 * 65536;         // 3*65536
    float* Qf = (float*)(wlT + 3 * 65536); // NSL fp32 (full Q, probe input)

    hipMemsetAsync(hpub, 0, 256 * sizeof(unsigned long long), stream);

    splitw_kernel<<<dim3(3, 256), 256, 0, stream>>>(wq, wk, wv, whT, wlT);
    src_kernel<<<NROW, 256, 0, stream>>>(x, emb_w, emb_b, srch, srcl, srcrow);
    gemm_qkv_mfma<<<dim3(128, 2, 3), 256, 0, stream>>>(srch, srcl, whT, wlT,
                                                       bq, bk, bv, Qf, K, V, qrow);
    qks_probe<<<NROW / 4, 256, 0, stream>>>(Qf, K, sidx, Mv);
    rank_kernel<<<BB, 256, 0, stream>>>(Mv, flag);
    ctx_scores<<<dim3(BB, 16), 256, 0, stream>>>(qrow, K, flag, sc);
    ctx_softmax<<<BB, 256, 0, stream>>>(flag, sc, ssum);
    ctx_pv<<<dim3(BB, 8), 256, 0, stream>>>(V, sc, flag, part);
    tail_kernel<<<BB, 256, 0, stream>>>(srcrow, part, ssum, flag, wo, bo,
                                        c1w, c1b, c2w, c2b,
                                        ln1g, ln1b, ln2g, ln2b, lnfg, lnfb, enc);
    gru_coop_kernel<<<GB, 768, 0, stream>>>(enc, wih, whh, bih, bhh, fcw, fcb,
                                            hpub, (float*)d_out);
}

// Round 12
// 171.283 us; speedup vs baseline: 1.1261x; 1.0080x over previous
//
#include <hip/hip_runtime.h>
#include <hip/hip_bf16.h>
#include <math.h>

// Problem constants
#define BB 8
#define LL 2048
#define CIN 32
#define DD 256
#define UU 40   // sample_k = top-k size
#define NROW (BB*LL)          // 16384
#define NSL  (NROW*DD)        // 4194304 elements per (B,L,D) tensor
#define GB 8                  // GRU cooperative blocks

typedef unsigned short u16;
typedef __attribute__((ext_vector_type(8))) short short8;
typedef __attribute__((ext_vector_type(4))) float f32x4;

__device__ __forceinline__ u16 f2bf(float v) {
    unsigned u = __float_as_uint(v);
    unsigned r = (u + 0x7FFF + ((u >> 16) & 1)) >> 16;   // RNE
    return (u16)r;
}
__device__ __forceinline__ float bf2f(u16 h) {
    return __uint_as_float(((unsigned)h) << 16);
}

// DPP row reduction (VALU pipe). row_shr:N moves data toward HIGHER lanes,
// so the row total accumulates in the HIGHEST lane (15 of 16).
template<int CTRL>
__device__ __forceinline__ float dpp_add(float v) {
    int s = __builtin_amdgcn_update_dpp(0, __float_as_int(v), CTRL, 0xf, 0xf, true);
    return v + __int_as_float(s);
}
__device__ __forceinline__ float row16_sum(float v) {
    v = dpp_add<0x118>(v);  // row_shr:8
    v = dpp_add<0x114>(v);  // row_shr:4
    v = dpp_add<0x112>(v);  // row_shr:2
    v = dpp_add<0x111>(v);  // row_shr:1
    return v;
}
__device__ __forceinline__ float dot4(float4 a, float4 b) {
    return a.x * b.x + a.y * b.y + a.z * b.z + a.w * b.w;
}

// ---------------------------------------------------------------------------
// Kernel A: src = x @ emb_w + emb_b + pos_encoding -> bf16 hi/lo split
__global__ __launch_bounds__(256) void src_kernel(
    const float* __restrict__ x, const float* __restrict__ emb_w,
    const float* __restrict__ emb_b,
    u16* __restrict__ srch, u16* __restrict__ srcl, float* __restrict__ srcrow)
{
    __shared__ float xs[CIN];
    const int orig = blockIdx.x;
    const int b = orig & 7;
    const int l = orig >> 3;
    const int r = (b << 11) | l;
    const int d = threadIdx.x;
    if (d < CIN) xs[d] = x[(size_t)r * CIN + d];
    __syncthreads();
    float acc = emb_b[d];
#pragma unroll 8
    for (int c = 0; c < CIN; ++c) acc += xs[c] * emb_w[c * DD + d];
    const int i = d >> 1;
    const float ang = (float)l * expf((float)(2 * i) * (-9.210340371976184f / 256.0f));
    const float pe = (d & 1) ? cosf(ang) : sinf(ang);
    const float v = acc + pe;
    const u16 h = f2bf(v);
    srch[(size_t)r * DD + d] = h;
    srcl[(size_t)r * DD + d] = f2bf(v - bf2f(h));
    if (l == LL - 1) srcrow[b * DD + d] = v;
}

// ---------------------------------------------------------------------------
// Kernel A2: split + transpose weights: whT[o][n][k] = bf16(W_o[k][n])
__global__ __launch_bounds__(256) void splitw_kernel(
    const float* __restrict__ wq, const float* __restrict__ wk,
    const float* __restrict__ wv, u16* __restrict__ whT, u16* __restrict__ wlT)
{
    const int o = blockIdx.x, n = blockIdx.y, k = threadIdx.x;
    const float* W = (o == 0) ? wq : (o == 1) ? wk : wv;
    const float v = W[(size_t)k * DD + n];
    const u16 h = f2bf(v);
    whT[((size_t)o << 16) + n * DD + k] = h;
    wlT[((size_t)o << 16) + n * DD + k] = f2bf(v - bf2f(h));
}

// ---------------------------------------------------------------------------
// Kernel B1 v2: Q,K,V via MFMA, bf16x3 split precision, 128x128 tiles.
// grid (128, 2, 3); z: 0->Q 1->K 2->V. 768 blocks = 3/CU, all resident.
// 4 waves per block, each computing a 64x64 quadrant (4x4 fragments).
// NUMERICS BITWISE-IDENTICAL to the 64^2 version (same k-step sequence,
// same 3-term split order per step). Q epilogue writes qrow.
__global__ __launch_bounds__(256) void gemm_qkv_mfma(
    const u16* __restrict__ srch, const u16* __restrict__ srcl,
    const u16* __restrict__ whT, const u16* __restrict__ wlT,
    const float* __restrict__ bq, const float* __restrict__ bk,
    const float* __restrict__ bv,
    float* __restrict__ Qf, float* __restrict__ K, float* __restrict__ V,
    float* __restrict__ qrow)
{
    __shared__ __align__(16) u16 AhS[128][40], AlS[128][40],
                                 BhS[128][40], BlS[128][40];   // 40 KB
    const int t = threadIdx.x;
    const int bx = blockIdx.x;                  // 0..127
    const int mt = (bx & 7) * 16 + (bx >> 3);   // batch (bx&7) -> XCD (bx&7)
    const int bm = mt * 128;
    const int bn = blockIdx.y * 128;            // 0 or 128
    const int o  = blockIdx.z;                  // 0->Q, 1->K, 2->V
    const u16* wh = whT + ((size_t)o << 16);
    const u16* wl = wlT + ((size_t)o << 16);
    const float* bias = (o == 0) ? bq : (o == 1) ? bk : bv;
    float* C = (o == 0) ? Qf : (o == 1) ? K : V;

    const int lane = t & 63, w = t >> 6;
    const int wr = (w >> 1) * 64, wc = (w & 1) * 64;  // wave quadrant origin
    const int frow = lane & 15, kg = (lane >> 4) * 8;

    f32x4 acc[4][4];
#pragma unroll
    for (int mf = 0; mf < 4; ++mf)
#pragma unroll
        for (int nf = 0; nf < 4; ++nf) acc[mf][nf] = (f32x4){0.f, 0.f, 0.f, 0.f};

    for (int ks = 0; ks < 8; ++ks) {
        const int kb = ks * 32;
        // stage 4 buffers of 128 rows x 32 cols; 512 short8 each, 2/thread
#pragma unroll
        for (int e0 = 0; e0 < 512; e0 += 256) {
            const int e = e0 + t;
            const int row = e >> 2, c8 = (e & 3) * 8;
            *(short8*)&AhS[row][c8] = *(const short8*)&srch[(size_t)(bm + row) * DD + kb + c8];
            *(short8*)&AlS[row][c8] = *(const short8*)&srcl[(size_t)(bm + row) * DD + kb + c8];
            *(short8*)&BhS[row][c8] = *(const short8*)&wh[(size_t)(bn + row) * DD + kb + c8];
            *(short8*)&BlS[row][c8] = *(const short8*)&wl[(size_t)(bn + row) * DD + kb + c8];
        }
        __syncthreads();
        // b-fragments once per k-step (reused across all 4 mf rows)
        short8 bhr[4], blr[4];
#pragma unroll
        for (int nf = 0; nf < 4; ++nf) {
            bhr[nf] = *(const short8*)&BhS[wc + nf * 16 + frow][kg];
            blr[nf] = *(const short8*)&BlS[wc + nf * 16 + frow][kg];
        }
#pragma unroll
        for (int mf = 0; mf < 4; ++mf) {
            const short8 ah = *(const short8*)&AhS[wr + mf * 16 + frow][kg];
            const short8 al = *(const short8*)&AlS[wr + mf * 16 + frow][kg];
#pragma unroll
            for (int nf = 0; nf < 4; ++nf) {
                acc[mf][nf] = __builtin_amdgcn_mfma_f32_16x16x32_bf16(al, bhr[nf], acc[mf][nf], 0, 0, 0);
                acc[mf][nf] = __builtin_amdgcn_mfma_f32_16x16x32_bf16(ah, blr[nf], acc[mf][nf], 0, 0, 0);
                acc[mf][nf] = __builtin_amdgcn_mfma_f32_16x16x32_bf16(ah, bhr[nf], acc[mf][nf], 0, 0, 0);
            }
        }
        __syncthreads();
    }
    // C/D layout (HW-verified): col = lane&15, row = (lane>>4)*4 + reg
#pragma unroll
    for (int mf = 0; mf < 4; ++mf) {
#pragma unroll
        for (int nf = 0; nf < 4; ++nf) {
#pragma unroll
            for (int r = 0; r < 4; ++r) {
                const int row = bm + wr + mf * 16 + (lane >> 4) * 4 + r;
                const int col = bn + wc + nf * 16 + (lane & 15);
                const float v = acc[mf][nf][r] + bias[col];
                C[(size_t)row * DD + col] = v;
                if (o == 0 && (row & (LL - 1)) == (LL - 1))
                    qrow[(row >> 11) * DD + col] = v;
            }
        }
    }
}

// ---------------------------------------------------------------------------
// Kernel B2 v6: FULLY-COALESCED gather (R11 winner: probe 47->~33us).
// One wave per row; for each of the 40 samples, ALL 64 lanes read the K row
// contiguously (lane l takes k[4l..4l+4), 64x16B = one clean 1KB run per
// instruction). Reduction: per-sample dot4 -> row16_sum within each 16-lane
// row -> 4 partials to LDS -> one thread per row combines serially.
__global__ __launch_bounds__(256) void qks_probe(
    const float* __restrict__ Qf, const float* __restrict__ Kf,
    const int* __restrict__ sidx, float* __restrict__ M)
{
    __shared__ float qkp[4][4][UU];   // [wave][sub16][sample] partials
    const int bid = blockIdx.x;
    const int b = bid & 7;              // batch -> XCD b (K L2-resident there)
    const int grp = bid >> 3;           // 0..511 row-group within batch
    const int t = threadIdx.x;
    const int wv = t >> 6;              // wave = row within group
    const int lane = t & 63;
    const int sub = lane >> 4;          // 16-lane row within the wave
    const int j = lane & 15;
    const int l = grp * 4 + wv;         // row within batch
    const size_t r = ((size_t)b << 11) + l;

    const int* si = sidx + (size_t)l * UU;
    // one coalesced 160B read per row covers all 40 indices
    const int myidx = si[lane < UU ? lane : 0];

    // per-lane q chunk: 4 consecutive floats (coalesced wave read of 1KB)
    const float4 q = *(const float4*)&Qf[r * DD + lane * 4];
    const float* Kb = Kf + ((size_t)b << 11) * DD;

#pragma unroll
    for (int s = 0; s < UU; ++s) {
        // wave-uniform row index (SGPR) -> saddr+lane*16B coalesced load
        const int idx = __builtin_amdgcn_readlane(myidx, s);
        const float4 kv = *(const float4*)&Kb[(size_t)idx * DD + lane * 4];
        float d = dot4(q, kv);
        d = row16_sum(d);               // lane j==15 of each 16-row holds partial
        if (j == 15) qkp[wv][sub][s] = d;
    }
    __syncthreads();
    if (t < 4) {
        float mx = -1e30f, sm = 0.0f;
#pragma unroll
        for (int s = 0; s < UU; ++s) {
            const float v = ((qkp[t][0][s] + qkp[t][1][s])
                           + qkp[t][2][s]) + qkp[t][3][s];
            mx = fmaxf(mx, v); sm += v;
        }
        M[((size_t)b << 11) + grp * 4 + t] = mx - sm * (1.0f / (float)LL);
    }
}

// ---------------------------------------------------------------------------
// Kernel D: flag[b] = (rank of M[b,2047]) < 40
__global__ __launch_bounds__(256) void rank_kernel(
    const float* __restrict__ M, int* __restrict__ flag)
{
    __shared__ int redi[256];
    const int b = blockIdx.x, t = threadIdx.x;
    const float* Mb = M + (size_t)b * LL;
    const float ref = Mb[LL - 1];
    int cnt = 0;
    for (int l = t; l < LL; l += 256)
        if (l != LL - 1 && Mb[l] >= ref) cnt++;
    redi[t] = cnt; __syncthreads();
    for (int s = 128; s; s >>= 1) { if (t < s) redi[t] += redi[t + s]; __syncthreads(); }
    if (t == 0) flag[b] = (redi[0] < UU) ? 1 : 0;
}

// ---------------------------------------------------------------------------
// Kernel E1: raw scores for row l=2047 (DPP), Q row from qrow buffer
__global__ __launch_bounds__(256) void ctx_scores(
    const float* __restrict__ qrow, const float* __restrict__ K,
    const int* __restrict__ flag, float* __restrict__ sc)
{
    const int b = blockIdx.x;
    if (!flag[b]) return;
    const int t = threadIdx.x, grp = t >> 4, j = t & 15;
    const size_t base = (size_t)b * LL * DD;
    const float4* qr = (const float4*)&qrow[b * DD];
    const float4 q0 = qr[j * 4 + 0], q1 = qr[j * 4 + 1],
                 q2 = qr[j * 4 + 2], q3 = qr[j * 4 + 3];
    const int k0 = blockIdx.y * 128 + grp * 8;
#pragma unroll
    for (int i = 0; i < 8; ++i) {
        const int k = k0 + i;
        const float4* kr = (const float4*)&K[base + (size_t)k * DD];
        float d = dot4(q0, kr[j * 4 + 0]) + dot4(q1, kr[j * 4 + 1])
                + dot4(q2, kr[j * 4 + 2]) + dot4(q3, kr[j * 4 + 3]);
        d = row16_sum(d);
        if (j == 15) sc[b * LL + k] = d * (1.0f / 16.0f);
    }
}

// Kernel E2: softmax numerators in place + denominator
__global__ __launch_bounds__(256) void ctx_softmax(
    const int* __restrict__ flag, float* __restrict__ sc, float* __restrict__ ssum)
{
    __shared__ float red[256];
    const int b = blockIdx.x;
    if (!flag[b]) return;
    const int t = threadIdx.x;
    float* s = sc + b * LL;
    float lm = -1e30f;
    for (int k = t; k < LL; k += 256) lm = fmaxf(lm, s[k]);
    red[t] = lm; __syncthreads();
    for (int st = 128; st; st >>= 1) { if (t < st) red[t] = fmaxf(red[t], red[t + st]); __syncthreads(); }
    const float mx = red[0]; __syncthreads();
    float ls = 0.0f;
    for (int k = t; k < LL; k += 256) { float e = expf(s[k] - mx); s[k] = e; ls += e; }
    red[t] = ls; __syncthreads();
    for (int st = 128; st; st >>= 1) { if (t < st) red[t] += red[t + st]; __syncthreads(); }
    if (t == 0) ssum[b] = red[0];
}

// Kernel E3: PV partials
__global__ __launch_bounds__(256) void ctx_pv(
    const float* __restrict__ V, const float* __restrict__ sc,
    const int* __restrict__ flag, float* __restrict__ part)
{
    const int b = blockIdx.x, slice = blockIdx.y;
    const int d = threadIdx.x;
    const size_t base = (size_t)b * LL * DD;
    const int k0 = slice * 256;
    float acc = 0.0f;
    if (flag[b]) {
#pragma unroll 4
        for (int k = k0; k < k0 + 256; ++k)
            acc += sc[b * LL + k] * V[base + (size_t)k * DD + d];
    } else {
#pragma unroll 4
        for (int k = k0; k < k0 + 256; ++k)
            acc += V[base + (size_t)k * DD + d];
    }
    part[(b * 8 + slice) * DD + d] = acc;
}

// ---------------------------------------------------------------------------
__device__ __forceinline__ float block_sum256(float v, float* red) {
    const int t = threadIdx.x;
    __syncthreads();
    red[t] = v; __syncthreads();
    for (int s = 128; s; s >>= 1) { if (t < s) red[t] += red[t + s]; __syncthreads(); }
    return red[0];
}

// Kernel F: per-batch tail at l=2047
__global__ __launch_bounds__(256) void tail_kernel(
    const float* __restrict__ srcrow, const float* __restrict__ part,
    const float* __restrict__ ssum, const int* __restrict__ flag,
    const float* __restrict__ wo, const float* __restrict__ bo,
    const float* __restrict__ c1w, const float* __restrict__ c1b,
    const float* __restrict__ c2w, const float* __restrict__ c2b,
    const float* __restrict__ g1, const float* __restrict__ b1,
    const float* __restrict__ g2, const float* __restrict__ b2,
    const float* __restrict__ gf, const float* __restrict__ bf,
    float* __restrict__ enc)
{
    __shared__ float xs[DD];
    __shared__ float red[DD];
    const int b = blockIdx.x, d = threadIdx.x;

    float cv = 0.0f;
#pragma unroll
    for (int i = 0; i < 8; ++i) cv += part[(b * 8 + i) * DD + d];
    cv = flag[b] ? cv / ssum[b] : cv * (1.0f / (float)LL);

    xs[d] = cv; __syncthreads();
    float o = bo[d];
    for (int j = 0; j < DD; ++j) o += xs[j] * wo[j * DD + d];
    const float v = srcrow[b * DD + d] + o;

    float mu = block_sum256(v, red) * (1.0f / DD);
    float dv = v - mu;
    float var = block_sum256(dv * dv, red) * (1.0f / DD);
    const float x1 = dv * rsqrtf(var + 1e-5f) * g1[d] + b1[d];

    __syncthreads(); xs[d] = x1; __syncthreads();
    float a = c1b[d];
    for (int j = 0; j < DD; ++j) a += xs[j] * c1w[j * DD + d];
    a = 0.5f * a * (1.0f + erff(a * 0.70710678118654752f));

    __syncthreads(); xs[d] = a; __syncthreads();
    float y = c2b[d];
    for (int j = 0; j < DD; ++j) y += xs[j] * c2w[j * DD + d];

    float t2 = x1 + y;
    mu = block_sum256(t2, red) * (1.0f / DD);
    dv = t2 - mu;
    var = block_sum256(dv * dv, red) * (1.0f / DD);
    float t3 = dv * rsqrtf(var + 1e-5f) * g2[d] + b2[d];

    mu = block_sum256(t3, red) * (1.0f / DD);
    dv = t3 - mu;
    var = block_sum256(dv * dv, red) * (1.0f / DD);
    enc[b * DD + d] = dv * rsqrtf(var + 1e-5f) * gf[d] + bf[d];
}

// ---------------------------------------------------------------------------
// GRU v4: XCD-COLOCATED cooperative blocks. v3 launched 8 blocks which the
// round-robin dispatcher spreads across 8 DIFFERENT XCDs — every one of the
// 8 sequential hidden-state exchanges (tagged publish + spin) crossed dies,
// the slowest possible visibility path. v4 launches 64 blocks and only
// bid%8==0 work (g = bid>>3): under round-robin, blocks 0,8,...,56 all land
// on XCD 0 (distinct CUs; 98.7KB LDS forces 1 block/CU; XCD0 has 32 CUs),
// so the hpub exchange stays inside one XCD's L2 (~200-400cy visibility).
// Placement is a perf heuristic only — AGENT-scope atomics are correct for
// any mapping (guide G16); compute and numerics are byte-identical to v3.
__global__ __launch_bounds__(768) void gru_coop_kernel(
    const float* __restrict__ enc, const float* __restrict__ wih,
    const float* __restrict__ whh, const float* __restrict__ bih,
    const float* __restrict__ bhh, const float* __restrict__ fcw,
    const float* __restrict__ fcb,
    unsigned long long* __restrict__ hpub,   // [256], zeroed per launch
    float* __restrict__ out)
{
    __shared__ float whhS[96][257];   // 98.7 KB
    __shared__ float encS[BB][260];
    __shared__ float giS[96][8];
    __shared__ float hS[DD];
    __shared__ float ghS[96];
    __shared__ float red[256];
    const int bid = blockIdx.x;
    if (bid & 7) return;              // workers: 0,8,...,56 -> same XCD
    const int g = bid >> 3, t = threadIdx.x;

#pragma unroll
    for (int i = 0; i < 8; ++i) {
        const int f4 = t + 768 * i;          // 96 rows x 64 float4
        const int lr = f4 >> 6, c4 = f4 & 63;
        const int R = (lr >> 5) * 256 + g * 32 + (lr & 31);
        const float4 w = *(const float4*)&whh[(size_t)R * DD + c4 * 4];
        whhS[lr][c4 * 4 + 0] = w.x; whhS[lr][c4 * 4 + 1] = w.y;
        whhS[lr][c4 * 4 + 2] = w.z; whhS[lr][c4 * 4 + 3] = w.w;
    }
    for (int e = t; e < BB * DD; e += 768) encS[e >> 8][e & 255] = enc[e];
    if (t < DD) hS[t] = 0.0f;
    __syncthreads();

    {
        const int lr = t >> 3, b = t & 7;
        const int R = (lr >> 5) * 256 + g * 32 + (lr & 31);
        float acc = bih[R];
        const float4* w4 = (const float4*)&wih[(size_t)R * DD];
#pragma unroll 8
        for (int jc = 0; jc < 64; ++jc) {
            const float4 w = w4[jc];
            acc += encS[b][jc * 4 + 0] * w.x + encS[b][jc * 4 + 1] * w.y
                 + encS[b][jc * 4 + 2] * w.z + encS[b][jc * 4 + 3] * w.w;
        }
        giS[lr][b] = acc;
    }
    __syncthreads();

    for (int step = 1; step <= BB; ++step) {
        const int b = step - 1;
        const int lr = t >> 3, s = t & 7;
        float p = 0.0f;
#pragma unroll
        for (int k = 0; k < 32; ++k) {
            const int c = s * 32 + ((k + s * 4) & 31);
            p += whhS[lr][c] * hS[c];
        }
        p = dpp_add<0x114>(p); p = dpp_add<0x112>(p); p = dpp_add<0x111>(p);
        if (s == 7) ghS[lr] = p + bhh[(lr >> 5) * 256 + g * 32 + (lr & 31)];
        __syncthreads();

        if (t < 32) {
            const float r  = 1.0f / (1.0f + expf(-(giS[t][b]      + ghS[t])));
            const float z  = 1.0f / (1.0f + expf(-(giS[32 + t][b] + ghS[32 + t])));
            const float n  = tanhf(giS[64 + t][b] + r * ghS[64 + t]);
            const float hnew = (1.0f - z) * n + z * hS[g * 32 + t];
            const unsigned long long w =
                ((unsigned long long)(unsigned)step << 32) | (unsigned long long)__float_as_uint(hnew);
            __hip_atomic_store(&hpub[g * 32 + t], w, __ATOMIC_RELAXED, __HIP_MEMORY_SCOPE_AGENT);
        }
        __syncthreads();
        if (t < DD) {
            unsigned long long w;
            do {
                w = __hip_atomic_load(&hpub[t], __ATOMIC_RELAXED, __HIP_MEMORY_SCOPE_AGENT);
            } while ((int)(w >> 32) != step);
            hS[t] = __uint_as_float((unsigned)w);
        }
        __syncthreads();

        if (g == 0) {
            if (t < DD) red[t] = hS[t] * fcw[t];
            __syncthreads();
            for (int st2 = 128; st2; st2 >>= 1) { if (t < st2) red[t] += red[t + st2]; __syncthreads(); }
            if (t == 0) out[b] = red[0] + fcb[0];
            __syncthreads();
        }
    }
}

// ---------------------------------------------------------------------------
extern "C" void kernel_launch(void* const* d_in, const int* in_sizes, int n_in,
                              void* d_out, int out_size, void* d_ws, size_t ws_size,
                              hipStream_t stream)
{
    const float* x      = (const float*)d_in[0];
    const int*   sidx   = (const int*)  d_in[1];
    const float* emb_w  = (const float*)d_in[2];
    const float* emb_b  = (const float*)d_in[3];
    const float* wq     = (const float*)d_in[4];
    const float* bq     = (const float*)d_in[5];
    const float* wk     = (const float*)d_in[6];
    const float* bk     = (const float*)d_in[7];
    const float* wv     = (const float*)d_in[8];
    const float* bv     = (const float*)d_in[9];
    const float* wo     = (const float*)d_in[10];
    const float* bo     = (const float*)d_in[11];
    const float* c1w    = (const float*)d_in[12];
    const float* c1b    = (const float*)d_in[13];
    const float* c2w    = (const float*)d_in[14];
    const float* c2b    = (const float*)d_in[15];
    const float* ln1g   = (const float*)d_in[16];
    const float* ln1b   = (const float*)d_in[17];
    const float* ln2g   = (const float*)d_in[18];
    const float* ln2b   = (const float*)d_in[19];
    const float* lnfg   = (const float*)d_in[20];
    const float* lnfb   = (const float*)d_in[21];
    const float* wih    = (const float*)d_in[22];
    const float* whh    = (const float*)d_in[23];
    const float* bih    = (const float*)d_in[24];
    const float* bhh    = (const float*)d_in[25];
    const float* fcw    = (const float*)d_in[26];
    const float* fcb    = (const float*)d_in[27];

    float* ws  = (float*)d_ws;
    float* K    = ws;                    // NSL
    float* V    = K + NSL;               // NSL
    float* Mv   = V + NSL;               // 16384
    int*   flag = (int*)(Mv + NROW);     // 16
    float* sc   = (float*)(flag + 16);   // 8*2048
    float* ssum = sc + BB * LL;          // 16
    float* part = ssum + 16;             // 8*8*256
    float* srcrow = part + BB * 8 * DD;  // 2048
    float* qrow = srcrow + BB * DD;      // 2048
    float* enc  = qrow + BB * DD;        // 2048
    unsigned long long* hpub = (unsigned long long*)(enc + BB * DD); // 256
    u16* srch = (u16*)(hpub + 256);      // NSL bf16
    u16* srcl = srch + NSL;              // NSL bf16
    u16* whT  = srcl + NSL;              // 3*65536
    u16* wlT  = whT + 3 * 65536;         // 3*65536
    float* Qf = (float*)(wlT + 3 * 65536); // NSL fp32 (full Q, probe input)

    hipMemsetAsync(hpub, 0, 256 * sizeof(unsigned long long), stream);

    splitw_kernel<<<dim3(3, 256), 256, 0, stream>>>(wq, wk, wv, whT, wlT);
    src_kernel<<<NROW, 256, 0, stream>>>(x, emb_w, emb_b, srch, srcl, srcrow);
    gemm_qkv_mfma<<<dim3(128, 2, 3), 256, 0, stream>>>(srch, srcl, whT, wlT,
                                                       bq, bk, bv, Qf, K, V, qrow);
    qks_probe<<<NROW / 4, 256, 0, stream>>>(Qf, K, sidx, Mv);
    rank_kernel<<<BB, 256, 0, stream>>>(Mv, flag);
    ctx_scores<<<dim3(BB, 16), 256, 0, stream>>>(qrow, K, flag, sc);
    ctx_softmax<<<BB, 256, 0, stream>>>(flag, sc, ssum);
    ctx_pv<<<dim3(BB, 8), 256, 0, stream>>>(V, sc, flag, part);
    tail_kernel<<<BB, 256, 0, stream>>>(srcrow, part, ssum, flag, wo, bo,
                                        c1w, c1b, c2w, c2b,
                                        ln1g, ln1b, ln2g, ln2b, lnfg, lnfb, enc);
    gru_coop_kernel<<<GB * 8, 768, 0, stream>>>(enc, wih, whh, bih, bhh, fcw, fcb,
                                                hpub, (float*)d_out);
}